// Round 1
// baseline (110.770 us; speedup 1.0000x reference)
//
#include <hip/hip_runtime.h>

#define NV 2
#define NC 64
#define NH 128
#define NW 416
#define NHW (NH * NW)          // 53248
#define NPT 262144
#define HWBLK (NHW / 64)       // 832

// ---------------- kernel 0: detect mask encoding ----------------
// int32-encoded bool mask: bytes at offset %4 != 0 are always 0.
// byte-encoded bool mask: ~70% of all bytes are 1.
__global__ void sfa_detect(const unsigned char* __restrict__ mask,
                           int* __restrict__ flag) {
    __shared__ int cnt;
    if (threadIdx.x == 0) cnt = 0;
    __syncthreads();
    int local = 0;
    for (int i = threadIdx.x; i < 1024; i += 256)
        if ((i & 3) != 0 && mask[i] != 0) local++;
    if (local) atomicAdd(&cnt, local);
    __syncthreads();
    if (threadIdx.x == 0) flag[0] = (cnt > 8) ? 1 : 0;   // 1 = byte-encoded
}

// ---------------- kernel 1: transpose (V,C,HW) -> (V,HW,C) ----------------
__global__ __launch_bounds__(256) void sfa_transpose(const float* __restrict__ x2d,
                                                     float* __restrict__ xT) {
    __shared__ float tile[64][68];
    const int b = blockIdx.x;            // 0 .. NV*HWBLK-1
    const int v = b / HWBLK;
    const int hw0 = (b % HWBLK) * 64;
    const int t = threadIdx.x;
    const int l16 = t & 15;
    const int g = t >> 4;                // 0..15

    const float* src = x2d + (size_t)v * NC * NHW;
#pragma unroll
    for (int k = 0; k < 4; ++k) {
        int c = g + 16 * k;
        float4 val = *(const float4*)(src + (size_t)c * NHW + hw0 + l16 * 4);
        *(float4*)&tile[c][l16 * 4] = val;
    }
    __syncthreads();
    float* dst = xT + ((size_t)v * NHW + hw0) * NC;
#pragma unroll
    for (int k = 0; k < 4; ++k) {
        int j = g + 16 * k;
        int c = l16 * 4;
        float4 o;
        o.x = tile[c + 0][j];
        o.y = tile[c + 1][j];
        o.z = tile[c + 2][j];
        o.w = tile[c + 3][j];
        *(float4*)(dst + (size_t)j * NC + c) = o;
    }
}

// ---------------- kernel 2: main SFA ----------------
// One wave per point (lane = channel). Block of 256 = 4 waves handles 64
// consecutive points; results staged in LDS for coalesced float4 writes.
template <bool TRANS>
__global__ __launch_bounds__(256) void sfa_main(const float* __restrict__ src,
                                                const int* __restrict__ pix,
                                                const unsigned char* __restrict__ maskb,
                                                const int* __restrict__ flagp,
                                                float* __restrict__ out) {
    __shared__ float tile[64][68];
    const int byteMask = flagp[0];
    const int t = threadIdx.x;
    const int lane = t & 63;
    const int wv = t >> 6;
    const int n0 = blockIdx.x * 64;

    for (int i = 0; i < 16; ++i) {
        const int pt = (wv << 4) + i;
        const int n = n0 + pt;
        float fv[2];
        int cv[2];
#pragma unroll
        for (int v = 0; v < 2; ++v) {
            const int4* pp = (const int4*)(pix + (((size_t)v * NPT + n) << 3));
            int4 a = pp[0];            // x0,y0,x1,y1
            int4 b = pp[1];            // x2,y2,x3,y3
            int i0 = a.y * NW + a.x;
            int i1 = a.w * NW + a.z;
            int i2 = b.y * NW + b.x;
            int i3 = b.w * NW + b.z;
            int m0, m1, m2, m3;
            size_t moff = ((size_t)v * NPT + n) << 2;
            if (byteMask) {
                uchar4 m = *(const uchar4*)(maskb + moff);
                m0 = m.x; m1 = m.y; m2 = m.z; m3 = m.w;
            } else {
                int4 m = *(const int4*)((const int*)maskb + moff);
                m0 = m.x; m1 = m.y; m2 = m.z; m3 = m.w;
            }
            float v0, v1, v2, v3;
            if (TRANS) {
                const float* base = src + (((size_t)v * NHW) << 6) + lane;
                v0 = base[(size_t)i0 << 6];
                v1 = base[(size_t)i1 << 6];
                v2 = base[(size_t)i2 << 6];
                v3 = base[(size_t)i3 << 6];
            } else {
                const float* base = src + (size_t)(v * NC + lane) * NHW;
                v0 = base[i0];
                v1 = base[i1];
                v2 = base[i2];
                v3 = base[i3];
            }
            float s = (m0 ? v0 : 0.f) + (m1 ? v1 : 0.f) +
                      (m2 ? v2 : 0.f) + (m3 ? v3 : 0.f);
            int c = (m0 ? 1 : 0) + (m1 ? 1 : 0) + (m2 ? 1 : 0) + (m3 ? 1 : 0);
            float rcp = (c == 0) ? 0.f
                      : (c == 1) ? 1.f
                      : (c == 2) ? 0.5f
                      : (c == 3) ? (1.f / 3.f)
                                 : 0.25f;
            fv[v] = s * rcp;
            cv[v] = c;
        }
        float f0 = fv[0], f1 = fv[1];
        float d = f0 * f1, q0 = f0 * f0, q1 = f1 * f1;
#pragma unroll
        for (int m = 1; m < 64; m <<= 1) {
            d  += __shfl_xor(d, m, 64);
            q0 += __shfl_xor(q0, m, 64);
            q1 += __shfl_xor(q1, m, 64);
        }
        float cosv = d * rsqrtf(fmaxf(q0 * q1, 1e-16f));
        float w0 = cv[0] > 0 ? 1.f : 0.f;
        float w1 = cv[1] > 0 ? 1.f : 0.f;
        float cw = cosv * w0 * w1;
        float wi = (w0 > w1) ? 1.f : 0.f;
        float wj = (w1 > w0) ? 1.f : 0.f;
        float o = ((cw + wi) * f0 + (cw + wj) * f1) * 0.5f;
        tile[lane][pt] = o;
    }
    __syncthreads();
    const int c = t >> 2;
    const int jb = (t & 3) << 4;
    float* op = out + (size_t)c * NPT + n0 + jb;
#pragma unroll
    for (int k = 0; k < 4; ++k) {
        float4 o4 = *(const float4*)&tile[c][jb + (k << 2)];
        *(float4*)(op + (k << 2)) = o4;
    }
}

extern "C" void kernel_launch(void* const* d_in, const int* in_sizes, int n_in,
                              void* d_out, int out_size, void* d_ws, size_t ws_size,
                              hipStream_t stream) {
    const float* x2d = (const float*)d_in[0];
    const int* pix = (const int*)d_in[1];
    const unsigned char* mask = (const unsigned char*)d_in[2];
    float* out = (float*)d_out;

    int* flag = (int*)d_ws;
    float* xT = (float*)((char*)d_ws + 256);
    const size_t need = 256 + (size_t)NV * NHW * NC * sizeof(float);

    sfa_detect<<<1, 256, 0, stream>>>(mask, flag);
    if (ws_size >= need) {
        sfa_transpose<<<NV * HWBLK, 256, 0, stream>>>(x2d, xT);
        sfa_main<true><<<NPT / 64, 256, 0, stream>>>(xT, pix, mask, flag, out);
    } else {
        sfa_main<false><<<NPT / 64, 256, 0, stream>>>(x2d, pix, mask, flag, out);
    }
}

// Round 2
// 73.844 us; speedup vs baseline: 1.5001x; 1.5001x over previous
//
#include <hip/hip_runtime.h>
#include <hip/hip_fp16.h>

#define NV 2
#define NC 64
#define NH 128
#define NW 416
#define NHW (NH * NW)          // 53248
#define NPT 262144
#define HWBLK (NHW / 64)       // 832

// ---------------- kernel 0: detect mask encoding ----------------
// int32-encoded bool mask: bytes at offset %4 != 0 are always 0.
// byte-encoded bool mask: ~70% of all bytes are 1.
__global__ void sfa_detect(const unsigned char* __restrict__ mask,
                           int* __restrict__ flag) {
    __shared__ int cnt;
    if (threadIdx.x == 0) cnt = 0;
    __syncthreads();
    int local = 0;
    for (int i = threadIdx.x; i < 1024; i += 256)
        if ((i & 3) != 0 && mask[i] != 0) local++;
    if (local) atomicAdd(&cnt, local);
    __syncthreads();
    if (threadIdx.x == 0) flag[0] = (cnt > 8) ? 1 : 0;   // 1 = byte-encoded
}

// ---------------- kernel 1: transpose (V,C,HW) f32 -> (V,HW,C) f16 --------
__global__ __launch_bounds__(256) void sfa_transpose(const float* __restrict__ x2d,
                                                     __half* __restrict__ xT) {
    __shared__ float tile[64][68];
    const int b = blockIdx.x;            // 0 .. NV*HWBLK-1
    const int v = b / HWBLK;
    const int hw0 = (b % HWBLK) * 64;
    const int t = threadIdx.x;
    const int l16 = t & 15;
    const int g = t >> 4;                // 0..15

    const float* src = x2d + (size_t)v * NC * NHW;
#pragma unroll
    for (int k = 0; k < 4; ++k) {
        int c = g + 16 * k;
        float4 val = *(const float4*)(src + (size_t)c * NHW + hw0 + l16 * 4);
        *(float4*)&tile[c][l16 * 4] = val;
    }
    __syncthreads();
    // write (hw, c) in half: pixel row = 64 half = 128 B
    uint2* dst = (uint2*)(xT + ((size_t)v * NHW + hw0) * NC);
#pragma unroll
    for (int k = 0; k < 4; ++k) {
        int j = g + 16 * k;              // pixel within tile
        int c = l16 * 4;                 // first channel
        __half2 h01 = __floats2half2_rn(tile[c + 0][j], tile[c + 1][j]);
        __half2 h23 = __floats2half2_rn(tile[c + 2][j], tile[c + 3][j]);
        uint2 o;
        o.x = *(unsigned*)&h01;
        o.y = *(unsigned*)&h23;
        dst[(size_t)j * 16 + l16] = o;
    }
}

// ---------------- kernel 2: main SFA (fp16 table, 2 points / wave-iter) ----
// lane l in [0,32) of group g owns channels (2l, 2l+1) of point 2i+g.
__global__ __launch_bounds__(256) void sfa_main2(const unsigned* __restrict__ xT,
                                                 const int* __restrict__ pix,
                                                 const unsigned char* __restrict__ maskb,
                                                 const int* __restrict__ flagp,
                                                 float* __restrict__ out) {
    __shared__ float tile[64][68];
    const int byteMask = flagp[0];
    const int t = threadIdx.x;
    const int lane = t & 63;
    const int l = lane & 31;
    const int g = lane >> 5;
    const int wv = t >> 6;
    const int n0 = blockIdx.x * 64;

#pragma unroll 2
    for (int i = 0; i < 8; ++i) {
        const int pt = (wv << 4) + (i << 1) + g;
        const int n = n0 + pt;
        float2 f[2];
        int cv[2];
#pragma unroll
        for (int v = 0; v < 2; ++v) {
            const int4* pp = (const int4*)(pix + (((size_t)v * NPT + n) << 3));
            int4 a = pp[0];            // x0,y0,x1,y1
            int4 b = pp[1];            // x2,y2,x3,y3
            unsigned i0 = (unsigned)(a.y * NW + a.x);
            unsigned i1 = (unsigned)(a.w * NW + a.z);
            unsigned i2 = (unsigned)(b.y * NW + b.x);
            unsigned i3 = (unsigned)(b.w * NW + b.z);
            int m0, m1, m2, m3;
            size_t moff = ((size_t)v * NPT + n) << 2;
            if (byteMask) {
                uchar4 m = *(const uchar4*)(maskb + moff);
                m0 = m.x; m1 = m.y; m2 = m.z; m3 = m.w;
            } else {
                int4 m = *(const int4*)((const int*)maskb + moff);
                m0 = m.x; m1 = m.y; m2 = m.z; m3 = m.w;
            }
            const unsigned* bu = xT + ((size_t)v * NHW) * 32u;
            unsigned u0 = bu[(i0 << 5) + l];
            unsigned u1 = bu[(i1 << 5) + l];
            unsigned u2 = bu[(i2 << 5) + l];
            unsigned u3 = bu[(i3 << 5) + l];
            u0 = m0 ? u0 : 0u;
            u1 = m1 ? u1 : 0u;
            u2 = m2 ? u2 : 0u;
            u3 = m3 ? u3 : 0u;
            __half2 s = __hadd2(__hadd2(*(__half2*)&u0, *(__half2*)&u1),
                                __hadd2(*(__half2*)&u2, *(__half2*)&u3));
            int c = (m0 ? 1 : 0) + (m1 ? 1 : 0) + (m2 ? 1 : 0) + (m3 ? 1 : 0);
            float rcp = (c == 0) ? 0.f
                      : (c == 1) ? 1.f
                      : (c == 2) ? 0.5f
                      : (c == 3) ? (1.f / 3.f)
                                 : 0.25f;
            float2 sf = __half22float2(s);
            f[v].x = sf.x * rcp;
            f[v].y = sf.y * rcp;
            cv[v] = c;
        }
        float2 f0 = f[0], f1 = f[1];
        float d  = f0.x * f1.x + f0.y * f1.y;
        float q0 = f0.x * f0.x + f0.y * f0.y;
        float q1 = f1.x * f1.x + f1.y * f1.y;
#pragma unroll
        for (int m = 1; m < 32; m <<= 1) {
            d  += __shfl_xor(d, m, 64);
            q0 += __shfl_xor(q0, m, 64);
            q1 += __shfl_xor(q1, m, 64);
        }
        float cosv = d * rsqrtf(fmaxf(q0 * q1, 1e-16f));
        float w0 = cv[0] > 0 ? 1.f : 0.f;
        float w1 = cv[1] > 0 ? 1.f : 0.f;
        float cw = cosv * w0 * w1;
        float wi = (w0 > w1) ? 1.f : 0.f;
        float wj = (w1 > w0) ? 1.f : 0.f;
        float ox = ((cw + wi) * f0.x + (cw + wj) * f1.x) * 0.5f;
        float oy = ((cw + wi) * f0.y + (cw + wj) * f1.y) * 0.5f;
        tile[2 * l + 0][pt] = ox;
        tile[2 * l + 1][pt] = oy;
    }
    __syncthreads();
    const int c = t >> 2;
    const int jb = (t & 3) << 4;
    float* op = out + (size_t)c * NPT + n0 + jb;
#pragma unroll
    for (int k = 0; k < 4; ++k) {
        float4 o4 = *(const float4*)&tile[c][jb + (k << 2)];
        *(float4*)(op + (k << 2)) = o4;
    }
}

// ---------------- fallback: direct gather from (V,C,H,W) f32 ----------------
__global__ __launch_bounds__(256) void sfa_main_fb(const float* __restrict__ src,
                                                   const int* __restrict__ pix,
                                                   const unsigned char* __restrict__ maskb,
                                                   const int* __restrict__ flagp,
                                                   float* __restrict__ out) {
    __shared__ float tile[64][68];
    const int byteMask = flagp[0];
    const int t = threadIdx.x;
    const int lane = t & 63;
    const int wv = t >> 6;
    const int n0 = blockIdx.x * 64;

    for (int i = 0; i < 16; ++i) {
        const int pt = (wv << 4) + i;
        const int n = n0 + pt;
        float fv[2];
        int cv[2];
#pragma unroll
        for (int v = 0; v < 2; ++v) {
            const int4* pp = (const int4*)(pix + (((size_t)v * NPT + n) << 3));
            int4 a = pp[0];
            int4 b = pp[1];
            int i0 = a.y * NW + a.x;
            int i1 = a.w * NW + a.z;
            int i2 = b.y * NW + b.x;
            int i3 = b.w * NW + b.z;
            int m0, m1, m2, m3;
            size_t moff = ((size_t)v * NPT + n) << 2;
            if (byteMask) {
                uchar4 m = *(const uchar4*)(maskb + moff);
                m0 = m.x; m1 = m.y; m2 = m.z; m3 = m.w;
            } else {
                int4 m = *(const int4*)((const int*)maskb + moff);
                m0 = m.x; m1 = m.y; m2 = m.z; m3 = m.w;
            }
            const float* base = src + (size_t)(v * NC + lane) * NHW;
            float v0 = base[i0], v1 = base[i1], v2 = base[i2], v3 = base[i3];
            float s = (m0 ? v0 : 0.f) + (m1 ? v1 : 0.f) +
                      (m2 ? v2 : 0.f) + (m3 ? v3 : 0.f);
            int c = (m0 ? 1 : 0) + (m1 ? 1 : 0) + (m2 ? 1 : 0) + (m3 ? 1 : 0);
            float rcp = (c == 0) ? 0.f
                      : (c == 1) ? 1.f
                      : (c == 2) ? 0.5f
                      : (c == 3) ? (1.f / 3.f)
                                 : 0.25f;
            fv[v] = s * rcp;
            cv[v] = c;
        }
        float f0 = fv[0], f1 = fv[1];
        float d = f0 * f1, q0 = f0 * f0, q1 = f1 * f1;
#pragma unroll
        for (int m = 1; m < 64; m <<= 1) {
            d  += __shfl_xor(d, m, 64);
            q0 += __shfl_xor(q0, m, 64);
            q1 += __shfl_xor(q1, m, 64);
        }
        float cosv = d * rsqrtf(fmaxf(q0 * q1, 1e-16f));
        float w0 = cv[0] > 0 ? 1.f : 0.f;
        float w1 = cv[1] > 0 ? 1.f : 0.f;
        float cw = cosv * w0 * w1;
        float wi = (w0 > w1) ? 1.f : 0.f;
        float wj = (w1 > w0) ? 1.f : 0.f;
        float o = ((cw + wi) * f0 + (cw + wj) * f1) * 0.5f;
        tile[lane][pt] = o;
    }
    __syncthreads();
    const int c = t >> 2;
    const int jb = (t & 3) << 4;
    float* op = out + (size_t)c * NPT + n0 + jb;
#pragma unroll
    for (int k = 0; k < 4; ++k) {
        float4 o4 = *(const float4*)&tile[c][jb + (k << 2)];
        *(float4*)(op + (k << 2)) = o4;
    }
}

extern "C" void kernel_launch(void* const* d_in, const int* in_sizes, int n_in,
                              void* d_out, int out_size, void* d_ws, size_t ws_size,
                              hipStream_t stream) {
    const float* x2d = (const float*)d_in[0];
    const int* pix = (const int*)d_in[1];
    const unsigned char* mask = (const unsigned char*)d_in[2];
    float* out = (float*)d_out;

    int* flag = (int*)d_ws;
    __half* xT = (__half*)((char*)d_ws + 256);
    const size_t need = 256 + (size_t)NV * NHW * NC * sizeof(__half);

    sfa_detect<<<1, 256, 0, stream>>>(mask, flag);
    if (ws_size >= need) {
        sfa_transpose<<<NV * HWBLK, 256, 0, stream>>>(x2d, xT);
        sfa_main2<<<NPT / 64, 256, 0, stream>>>((const unsigned*)xT, pix, mask,
                                                flag, out);
    } else {
        sfa_main_fb<<<NPT / 64, 256, 0, stream>>>(x2d, pix, mask, flag, out);
    }
}

// Round 3
// 67.431 us; speedup vs baseline: 1.6427x; 1.0951x over previous
//
#include <hip/hip_runtime.h>
#include <hip/hip_fp16.h>

#define NV 2
#define NC 64
#define NH 128
#define NW 416
#define NHW (NH * NW)          // 53248
#define NPT 262144
#define HWBLK (NHW / 64)       // 832

// ---------------- kernel 0: detect mask encoding ----------------
__global__ void sfa_detect(const unsigned char* __restrict__ mask,
                           int* __restrict__ flag) {
    __shared__ int cnt;
    if (threadIdx.x == 0) cnt = 0;
    __syncthreads();
    int local = 0;
    for (int i = threadIdx.x; i < 1024; i += 256)
        if ((i & 3) != 0 && mask[i] != 0) local++;
    if (local) atomicAdd(&cnt, local);
    __syncthreads();
    if (threadIdx.x == 0) flag[0] = (cnt > 8) ? 1 : 0;   // 1 = byte-encoded
}

// ---------------- kernel 1: transpose (V,C,HW) f32 -> (V,HW,C) f16 --------
__global__ __launch_bounds__(256) void sfa_transpose(const float* __restrict__ x2d,
                                                     __half* __restrict__ xT) {
    __shared__ float tile[64][68];
    const int b = blockIdx.x;            // 0 .. NV*HWBLK-1
    const int v = b / HWBLK;
    const int hw0 = (b % HWBLK) * 64;
    const int t = threadIdx.x;
    const int l16 = t & 15;
    const int g = t >> 4;                // 0..15

    const float* src = x2d + (size_t)v * NC * NHW;
#pragma unroll
    for (int k = 0; k < 4; ++k) {
        int c = g + 16 * k;
        float4 val = *(const float4*)(src + (size_t)c * NHW + hw0 + l16 * 4);
        *(float4*)&tile[c][l16 * 4] = val;
    }
    __syncthreads();
    uint2* dst = (uint2*)(xT + ((size_t)v * NHW + hw0) * NC);
#pragma unroll
    for (int k = 0; k < 4; ++k) {
        int j = g + 16 * k;              // pixel within tile
        int c = l16 * 4;                 // first channel
        __half2 h01 = __floats2half2_rn(tile[c + 0][j], tile[c + 1][j]);
        __half2 h23 = __floats2half2_rn(tile[c + 2][j], tile[c + 3][j]);
        uint2 o;
        o.x = *(unsigned*)&h01;
        o.y = *(unsigned*)&h23;
        dst[(size_t)j * 16 + l16] = o;
    }
}

static __device__ __forceinline__ unsigned hadd2u(unsigned a, unsigned b) {
    __half2 r = __hadd2(*(const __half2*)&a, *(const __half2*)&b);
    return *(unsigned*)&r;
}

// ---------------- kernel 2: main SFA ----------------
// 8 channels per lane (one dwordx4 of fp16 per pixel), 8 lanes per point,
// 8 points per wave-iteration, 2 iterations per wave.
__global__ __launch_bounds__(256) void sfa_main3(const unsigned* __restrict__ xT,
                                                 const int* __restrict__ pix,
                                                 const unsigned char* __restrict__ maskb,
                                                 const int* __restrict__ flagp,
                                                 float* __restrict__ out) {
    __shared__ float tile[64 * 64];
    const int byteMask = flagp[0];
    const int t = threadIdx.x;
    const int lane = t & 63;
    const int q = lane & 7;        // channel octet (ch 8q..8q+7)
    const int p = lane >> 3;       // point within the 8-point group
    const int wv = t >> 6;
    const int n0 = blockIdx.x * 64;

#pragma unroll
    for (int i = 0; i < 2; ++i) {
        const int pt = (wv << 4) + (i << 3) + p;
        const int n = n0 + pt;
        float f[2][8];
        int cv[2];
#pragma unroll
        for (int v = 0; v < 2; ++v) {
            const int4* pp = (const int4*)(pix + (((size_t)v * NPT + n) << 3));
            int4 a = pp[0];            // x0,y0,x1,y1
            int4 b = pp[1];            // x2,y2,x3,y3
            unsigned i0 = (unsigned)(a.y * NW + a.x);
            unsigned i1 = (unsigned)(a.w * NW + a.z);
            unsigned i2 = (unsigned)(b.y * NW + b.x);
            unsigned i3 = (unsigned)(b.w * NW + b.z);
            int m0, m1, m2, m3;
            size_t moff = ((size_t)v * NPT + n) << 2;
            if (byteMask) {
                uchar4 m = *(const uchar4*)(maskb + moff);
                m0 = m.x; m1 = m.y; m2 = m.z; m3 = m.w;
            } else {
                int4 m = *(const int4*)((const int*)maskb + moff);
                m0 = m.x; m1 = m.y; m2 = m.z; m3 = m.w;
            }
            // gather: one uint4 (8 fp16 channels) per pixel
            const unsigned* bu = xT + (((size_t)v * NHW) << 5) + (q << 2);
            uint4 u0 = *(const uint4*)(bu + ((size_t)i0 << 5));
            uint4 u1 = *(const uint4*)(bu + ((size_t)i1 << 5));
            uint4 u2 = *(const uint4*)(bu + ((size_t)i2 << 5));
            uint4 u3 = *(const uint4*)(bu + ((size_t)i3 << 5));
            u0.x = m0 ? u0.x : 0u; u0.y = m0 ? u0.y : 0u;
            u0.z = m0 ? u0.z : 0u; u0.w = m0 ? u0.w : 0u;
            u1.x = m1 ? u1.x : 0u; u1.y = m1 ? u1.y : 0u;
            u1.z = m1 ? u1.z : 0u; u1.w = m1 ? u1.w : 0u;
            u2.x = m2 ? u2.x : 0u; u2.y = m2 ? u2.y : 0u;
            u2.z = m2 ? u2.z : 0u; u2.w = m2 ? u2.w : 0u;
            u3.x = m3 ? u3.x : 0u; u3.y = m3 ? u3.y : 0u;
            u3.z = m3 ? u3.z : 0u; u3.w = m3 ? u3.w : 0u;
            unsigned s0 = hadd2u(hadd2u(u0.x, u1.x), hadd2u(u2.x, u3.x));
            unsigned s1 = hadd2u(hadd2u(u0.y, u1.y), hadd2u(u2.y, u3.y));
            unsigned s2 = hadd2u(hadd2u(u0.z, u1.z), hadd2u(u2.z, u3.z));
            unsigned s3 = hadd2u(hadd2u(u0.w, u1.w), hadd2u(u2.w, u3.w));
            int c = (m0 ? 1 : 0) + (m1 ? 1 : 0) + (m2 ? 1 : 0) + (m3 ? 1 : 0);
            float rcp = (c == 0) ? 0.f
                      : (c == 1) ? 1.f
                      : (c == 2) ? 0.5f
                      : (c == 3) ? (1.f / 3.f)
                                 : 0.25f;
            float2 f01 = __half22float2(*(const __half2*)&s0);
            float2 f23 = __half22float2(*(const __half2*)&s1);
            float2 f45 = __half22float2(*(const __half2*)&s2);
            float2 f67 = __half22float2(*(const __half2*)&s3);
            f[v][0] = f01.x * rcp; f[v][1] = f01.y * rcp;
            f[v][2] = f23.x * rcp; f[v][3] = f23.y * rcp;
            f[v][4] = f45.x * rcp; f[v][5] = f45.y * rcp;
            f[v][6] = f67.x * rcp; f[v][7] = f67.y * rcp;
            cv[v] = c;
        }
        float d = 0.f, q0 = 0.f, q1 = 0.f;
#pragma unroll
        for (int j = 0; j < 8; ++j) {
            d  = fmaf(f[0][j], f[1][j], d);
            q0 = fmaf(f[0][j], f[0][j], q0);
            q1 = fmaf(f[1][j], f[1][j], q1);
        }
#pragma unroll
        for (int m = 1; m < 8; m <<= 1) {
            d  += __shfl_xor(d, m, 64);
            q0 += __shfl_xor(q0, m, 64);
            q1 += __shfl_xor(q1, m, 64);
        }
        float cosv = d * rsqrtf(fmaxf(q0 * q1, 1e-16f));
        float w0 = cv[0] > 0 ? 1.f : 0.f;
        float w1 = cv[1] > 0 ? 1.f : 0.f;
        float cw = cosv * w0 * w1;
        float wi = (w0 > w1) ? 1.f : 0.f;
        float wj = (w1 > w0) ? 1.f : 0.f;
        float cw0 = (cw + wi) * 0.5f;
        float cw1 = (cw + wj) * 0.5f;
#pragma unroll
        for (int j = 0; j < 8; ++j) {
            int row = (q << 3) + j;
            tile[(row << 6) + ((pt + row) & 63)] = cw0 * f[0][j] + cw1 * f[1][j];
        }
    }
    __syncthreads();
    const int c = t >> 2;
    const int jb = (t & 3) << 4;
    float* op = out + (size_t)c * NPT + n0 + jb;
#pragma unroll
    for (int k = 0; k < 4; ++k) {
        float4 o4;
        o4.x = tile[(c << 6) + ((jb + (k << 2) + 0 + c) & 63)];
        o4.y = tile[(c << 6) + ((jb + (k << 2) + 1 + c) & 63)];
        o4.z = tile[(c << 6) + ((jb + (k << 2) + 2 + c) & 63)];
        o4.w = tile[(c << 6) + ((jb + (k << 2) + 3 + c) & 63)];
        *(float4*)(op + (k << 2)) = o4;
    }
}

// ---------------- fallback: direct gather from (V,C,H,W) f32 ----------------
__global__ __launch_bounds__(256) void sfa_main_fb(const float* __restrict__ src,
                                                   const int* __restrict__ pix,
                                                   const unsigned char* __restrict__ maskb,
                                                   const int* __restrict__ flagp,
                                                   float* __restrict__ out) {
    __shared__ float tile[64][68];
    const int byteMask = flagp[0];
    const int t = threadIdx.x;
    const int lane = t & 63;
    const int wv = t >> 6;
    const int n0 = blockIdx.x * 64;

    for (int i = 0; i < 16; ++i) {
        const int pt = (wv << 4) + i;
        const int n = n0 + pt;
        float fv[2];
        int cv[2];
#pragma unroll
        for (int v = 0; v < 2; ++v) {
            const int4* pp = (const int4*)(pix + (((size_t)v * NPT + n) << 3));
            int4 a = pp[0];
            int4 b = pp[1];
            int i0 = a.y * NW + a.x;
            int i1 = a.w * NW + a.z;
            int i2 = b.y * NW + b.x;
            int i3 = b.w * NW + b.z;
            int m0, m1, m2, m3;
            size_t moff = ((size_t)v * NPT + n) << 2;
            if (byteMask) {
                uchar4 m = *(const uchar4*)(maskb + moff);
                m0 = m.x; m1 = m.y; m2 = m.z; m3 = m.w;
            } else {
                int4 m = *(const int4*)((const int*)maskb + moff);
                m0 = m.x; m1 = m.y; m2 = m.z; m3 = m.w;
            }
            const float* base = src + (size_t)(v * NC + lane) * NHW;
            float v0 = base[i0], v1 = base[i1], v2 = base[i2], v3 = base[i3];
            float s = (m0 ? v0 : 0.f) + (m1 ? v1 : 0.f) +
                      (m2 ? v2 : 0.f) + (m3 ? v3 : 0.f);
            int c = (m0 ? 1 : 0) + (m1 ? 1 : 0) + (m2 ? 1 : 0) + (m3 ? 1 : 0);
            float rcp = (c == 0) ? 0.f
                      : (c == 1) ? 1.f
                      : (c == 2) ? 0.5f
                      : (c == 3) ? (1.f / 3.f)
                                 : 0.25f;
            fv[v] = s * rcp;
            cv[v] = c;
        }
        float f0 = fv[0], f1 = fv[1];
        float d = f0 * f1, q0 = f0 * f0, q1 = f1 * f1;
#pragma unroll
        for (int m = 1; m < 64; m <<= 1) {
            d  += __shfl_xor(d, m, 64);
            q0 += __shfl_xor(q0, m, 64);
            q1 += __shfl_xor(q1, m, 64);
        }
        float cosv = d * rsqrtf(fmaxf(q0 * q1, 1e-16f));
        float w0 = cv[0] > 0 ? 1.f : 0.f;
        float w1 = cv[1] > 0 ? 1.f : 0.f;
        float cw = cosv * w0 * w1;
        float wi = (w0 > w1) ? 1.f : 0.f;
        float wj = (w1 > w0) ? 1.f : 0.f;
        float o = ((cw + wi) * f0 + (cw + wj) * f1) * 0.5f;
        tile[lane][pt] = o;
    }
    __syncthreads();
    const int c = t >> 2;
    const int jb = (t & 3) << 4;
    float* op = out + (size_t)c * NPT + n0 + jb;
#pragma unroll
    for (int k = 0; k < 4; ++k) {
        float4 o4 = *(const float4*)&tile[c][jb + (k << 2)];
        *(float4*)(op + (k << 2)) = o4;
    }
}

extern "C" void kernel_launch(void* const* d_in, const int* in_sizes, int n_in,
                              void* d_out, int out_size, void* d_ws, size_t ws_size,
                              hipStream_t stream) {
    const float* x2d = (const float*)d_in[0];
    const int* pix = (const int*)d_in[1];
    const unsigned char* mask = (const unsigned char*)d_in[2];
    float* out = (float*)d_out;

    int* flag = (int*)d_ws;
    __half* xT = (__half*)((char*)d_ws + 256);
    const size_t need = 256 + (size_t)NV * NHW * NC * sizeof(__half);

    sfa_detect<<<1, 256, 0, stream>>>(mask, flag);
    if (ws_size >= need) {
        sfa_transpose<<<NV * HWBLK, 256, 0, stream>>>(x2d, xT);
        sfa_main3<<<NPT / 64, 256, 0, stream>>>((const unsigned*)xT, pix, mask,
                                                flag, out);
    } else {
        sfa_main_fb<<<NPT / 64, 256, 0, stream>>>(x2d, pix, mask, flag, out);
    }
}